// Round 1
// baseline (139.875 us; speedup 1.0000x reference)
//
#include <hip/hip_runtime.h>
#include <math.h>

// WaveletLayerND: fused mexican-hat wavelet + grouped 3x3 conv (kernel 1),
// then 1x1 channel mix (kernel 2). B=4, O=I=32, H=W=128, fp32 throughout.

#define RSTRIP 8   // output rows per wave

__global__ __launch_bounds__(256) void wavelet_grouped_conv(
    const float* __restrict__ x,      // (B, I, H, W)
    const float* __restrict__ scale,  // (O*I)
    const float* __restrict__ trans,  // (O*I)
    const float* __restrict__ wconv,  // (O, I, 3, 3)
    float* __restrict__ y,            // (B, O, H, W) workspace
    float mhc)
{
  const int lane  = threadIdx.x & 63;
  const int wave  = threadIdx.x >> 6;
  const int strip = blockIdx.x;          // 0..15
  const int b     = blockIdx.z;          // 0..3
  const int o     = blockIdx.y * 4 + wave; // 0..31 (one o per wave)
  const int r0    = strip * RSTRIP;
  const int c0    = lane << 1;           // this thread's two columns

  const float NHL2E = -0.72134752044448170f; // -0.5 * log2(e)

  float acc[RSTRIP][2];
#pragma unroll
  for (int r = 0; r < RSTRIP; ++r) { acc[r][0] = 0.f; acc[r][1] = 0.f; }

  const float* xb = x + (size_t)b * 32 * 128 * 128;

  for (int i = 0; i < 32; ++i) {
    // per-(o,i) scalars — force SGPR via readfirstlane (o is wave-uniform)
    const int oi = __builtin_amdgcn_readfirstlane(o * 32 + i);
    const float s   = scale[oi];
    const float t   = trans[oi];
    const float rs  = 1.0f / s;
    const float trs = t * rs;
    const float* wp = wconv + oi * 9;
    const float w00 = wp[0], w01 = wp[1], w02 = wp[2];
    const float w10 = wp[3], w11 = wp[4], w12 = wp[5];
    const float w20 = wp[6], w21 = wp[7], w22 = wp[8];
    const float* xi = xb + (size_t)i * 128 * 128;

#pragma unroll
    for (int j = 0; j < RSTRIP + 2; ++j) {
      const int ir = r0 + j - 1;           // input row (wave-uniform)
      if (ir >= 0 && ir < 128) {           // outside rows: wt = 0 (zero pad)
        const float2 xv = *(const float2*)(xi + ir * 128 + c0);
        // psi((x - t)/s) = MH_C * (u - 1) * exp(-u/2), u = sx^2
        const float sx0 = fmaf(xv.x, rs, -trs);
        const float sx1 = fmaf(xv.y, rs, -trs);
        const float u0 = sx0 * sx0, u1 = sx1 * sx1;
        const float e0 = __builtin_amdgcn_exp2f(u0 * NHL2E);
        const float e1 = __builtin_amdgcn_exp2f(u1 * NHL2E);
        const float p0 = fmaf(mhc, u0, -mhc) * e0;  // col c0
        const float p1 = fmaf(mhc, u1, -mhc) * e1;  // col c0+1
        // horizontal halo from neighbor lanes; image edges are zero padding
        float pl = __shfl_up(p1, 1);   // psi at col c0-1
        float pr = __shfl_down(p0, 1); // psi at col c0+2
        if (lane == 0)  pl = 0.f;
        if (lane == 63) pr = 0.f;

        // input row ir feeds output rows ir-1 (kh=2), ir (kh=1), ir+1 (kh=0)
        if (j <= RSTRIP - 1) {           // kh = 0 -> acc[j]
          acc[j][0] = fmaf(w00, pl, acc[j][0]);
          acc[j][0] = fmaf(w01, p0, acc[j][0]);
          acc[j][0] = fmaf(w02, p1, acc[j][0]);
          acc[j][1] = fmaf(w00, p0, acc[j][1]);
          acc[j][1] = fmaf(w01, p1, acc[j][1]);
          acc[j][1] = fmaf(w02, pr, acc[j][1]);
        }
        if (j >= 1 && j <= RSTRIP) {     // kh = 1 -> acc[j-1]
          acc[j-1][0] = fmaf(w10, pl, acc[j-1][0]);
          acc[j-1][0] = fmaf(w11, p0, acc[j-1][0]);
          acc[j-1][0] = fmaf(w12, p1, acc[j-1][0]);
          acc[j-1][1] = fmaf(w10, p0, acc[j-1][1]);
          acc[j-1][1] = fmaf(w11, p1, acc[j-1][1]);
          acc[j-1][1] = fmaf(w12, pr, acc[j-1][1]);
        }
        if (j >= 2) {                    // kh = 2 -> acc[j-2]
          acc[j-2][0] = fmaf(w20, pl, acc[j-2][0]);
          acc[j-2][0] = fmaf(w21, p0, acc[j-2][0]);
          acc[j-2][0] = fmaf(w22, p1, acc[j-2][0]);
          acc[j-2][1] = fmaf(w20, p0, acc[j-2][1]);
          acc[j-2][1] = fmaf(w21, p1, acc[j-2][1]);
          acc[j-2][1] = fmaf(w22, pr, acc[j-2][1]);
        }
      }
    }
  }

  float* yb = y + (((size_t)b * 32 + o) * 128 + r0) * 128 + c0;
#pragma unroll
  for (int r = 0; r < RSTRIP; ++r) {
    *(float2*)(yb + (size_t)r * 128) = make_float2(acc[r][0], acc[r][1]);
  }
}

__global__ __launch_bounds__(256) void mix1x1(
    const float* __restrict__ y,    // (B, O, H*W)
    const float* __restrict__ fw,   // (O_out, O_in)
    float* __restrict__ out)        // (B, O, H*W)
{
  const int px = blockIdx.x * 256 + threadIdx.x;  // 0..16383
  const int b  = blockIdx.y;
  const float* yb = y + (size_t)b * 32 * 16384 + px;
  float v[32];
#pragma unroll
  for (int o = 0; o < 32; ++o) v[o] = yb[(size_t)o * 16384];
  float* ob = out + (size_t)b * 32 * 16384 + px;
#pragma unroll
  for (int p = 0; p < 32; ++p) {
    float a = 0.f;
#pragma unroll
    for (int o = 0; o < 32; ++o) a = fmaf(fw[p * 32 + o], v[o], a);
    ob[(size_t)p * 16384] = a;
  }
}

extern "C" void kernel_launch(void* const* d_in, const int* in_sizes, int n_in,
                              void* d_out, int out_size, void* d_ws, size_t ws_size,
                              hipStream_t stream) {
  const float* x     = (const float*)d_in[0];
  const float* scale = (const float*)d_in[1];
  const float* trans = (const float*)d_in[2];
  const float* wconv = (const float*)d_in[3];
  const float* fw    = (const float*)d_in[4];
  float* out = (float*)d_out;
  float* y   = (float*)d_ws;   // 4*32*128*128 floats = 8.39 MB

  const float mhc = (float)(2.0 / (sqrt(3.0) * pow(M_PI, 0.25)));

  dim3 g1(128 / RSTRIP, 8, 4);   // (strips, o-groups of 4, b) = 512 blocks
  wavelet_grouped_conv<<<g1, 256, 0, stream>>>(x, scale, trans, wconv, y, mhc);

  dim3 g2(16384 / 256, 4);       // (pixel tiles, b)
  mix1x1<<<g2, 256, 0, stream>>>(y, fw, out);
}

// Round 2
// 96.967 us; speedup vs baseline: 1.4425x; 1.4425x over previous
//
#include <hip/hip_runtime.h>
#include <math.h>

// WaveletLayerND: fused mexican-hat wavelet + grouped 3x3 conv (kernel 1),
// then 1x1 channel mix (kernel 2). B=4, O=I=32, H=W=128, fp32 throughout.
//
// Kernel 1 layout: 512-thread blocks = 8 waves = 4 o-channels x 2 i-halves.
// Each wave accumulates conv over 16 input channels for an 8-row strip;
// the two i-halves reduce through LDS. 16 strips x 8 o-groups x 4 b = 512
// blocks -> 2 blocks/CU -> 16 waves/CU (50% occupancy) with halo cost 1.25x.

#define RSTRIP 8   // output rows per wave

__global__ __launch_bounds__(512) void wavelet_grouped_conv(
    const float* __restrict__ x,      // (B, I, H, W)
    const float* __restrict__ scale,  // (O*I)
    const float* __restrict__ trans,  // (O*I)
    const float* __restrict__ wconv,  // (O, I, 3, 3)
    float* __restrict__ y,            // (B, O, H, W) workspace
    float mhc)
{
  const int tid   = threadIdx.x;
  const int lane  = tid & 63;
  const int wave  = tid >> 6;          // 0..7
  const int w4    = wave & 3;          // which o within the block
  const int ihalf = wave >> 2;         // 0: i=0..15, 1: i=16..31
  const int strip = blockIdx.x;        // 0..15
  const int b     = blockIdx.z;        // 0..3
  const int o     = blockIdx.y * 4 + w4;
  const int r0    = strip * RSTRIP;
  const int c0    = lane << 1;         // this thread's two columns

  const float NHL2E = -0.72134752044448170f; // -0.5 * log2(e)

  float acc[RSTRIP][2];
#pragma unroll
  for (int r = 0; r < RSTRIP; ++r) { acc[r][0] = 0.f; acc[r][1] = 0.f; }

  const float* xb = x + (size_t)b * 32 * 128 * 128;

  for (int ii = 0; ii < 16; ii += 2) {
    const int i0 = (ihalf << 4) + ii;           // wave-uniform
    // per-(o,i) scalars -> SGPRs (oi uniform via readfirstlane)
    const int oi0 = __builtin_amdgcn_readfirstlane(o * 32 + i0);
    const int oi1 = oi0 + 1;
    const float rs0  = 1.0f / scale[oi0];
    const float trs0 = trans[oi0] * rs0;
    const float rs1  = 1.0f / scale[oi1];
    const float trs1 = trans[oi1] * rs1;
    const float* wpa = wconv + oi0 * 9;
    const float a00 = wpa[0], a01 = wpa[1], a02 = wpa[2];
    const float a10 = wpa[3], a11 = wpa[4], a12 = wpa[5];
    const float a20 = wpa[6], a21 = wpa[7], a22 = wpa[8];
    const float* wpb = wconv + oi1 * 9;
    const float b00 = wpb[0], b01 = wpb[1], b02 = wpb[2];
    const float b10 = wpb[3], b11 = wpb[4], b12 = wpb[5];
    const float b20 = wpb[6], b21 = wpb[7], b22 = wpb[8];
    const float* xi0 = xb + (size_t)i0 * 128 * 128;
    const float* xi1 = xi0 + 128 * 128;

#pragma unroll
    for (int j = 0; j < RSTRIP + 2; ++j) {
      const int ir = r0 + j - 1;           // input row (wave-uniform)
      if (ir >= 0 && ir < 128) {           // outside rows: wt = 0 (zero pad)
        const float2 xva = *(const float2*)(xi0 + ir * 128 + c0);
        const float2 xvb = *(const float2*)(xi1 + ir * 128 + c0);
        // psi((x - t)/s) = MH_C * (u - 1) * exp(-u/2), u = sx^2
        const float sa0 = fmaf(xva.x, rs0, -trs0);
        const float sa1 = fmaf(xva.y, rs0, -trs0);
        const float sb0 = fmaf(xvb.x, rs1, -trs1);
        const float sb1 = fmaf(xvb.y, rs1, -trs1);
        const float ua0 = sa0 * sa0, ua1 = sa1 * sa1;
        const float ub0 = sb0 * sb0, ub1 = sb1 * sb1;
        const float ea0 = __builtin_amdgcn_exp2f(ua0 * NHL2E);
        const float ea1 = __builtin_amdgcn_exp2f(ua1 * NHL2E);
        const float eb0 = __builtin_amdgcn_exp2f(ub0 * NHL2E);
        const float eb1 = __builtin_amdgcn_exp2f(ub1 * NHL2E);
        const float pa0 = fmaf(mhc, ua0, -mhc) * ea0;
        const float pa1 = fmaf(mhc, ua1, -mhc) * ea1;
        const float pb0 = fmaf(mhc, ub0, -mhc) * eb0;
        const float pb1 = fmaf(mhc, ub1, -mhc) * eb1;
        // horizontal halo from neighbor lanes; image edges zero-pad
        float pla = __shfl_up(pa1, 1);
        float pra = __shfl_down(pa0, 1);
        float plb = __shfl_up(pb1, 1);
        float prb = __shfl_down(pb0, 1);
        if (lane == 0)  { pla = 0.f; plb = 0.f; }
        if (lane == 63) { pra = 0.f; prb = 0.f; }

#define TAPS(W0, W1, W2, PL, P0, P1, PR, R)          \
        acc[R][0] = fmaf(W0, PL, acc[R][0]);         \
        acc[R][0] = fmaf(W1, P0, acc[R][0]);         \
        acc[R][0] = fmaf(W2, P1, acc[R][0]);         \
        acc[R][1] = fmaf(W0, P0, acc[R][1]);         \
        acc[R][1] = fmaf(W1, P1, acc[R][1]);         \
        acc[R][1] = fmaf(W2, PR, acc[R][1]);

        // input row ir feeds output rows ir+1 (kh=0), ir (kh=1), ir-1 (kh=2)
        if (j <= RSTRIP - 1) {
          TAPS(a00, a01, a02, pla, pa0, pa1, pra, j)
          TAPS(b00, b01, b02, plb, pb0, pb1, prb, j)
        }
        if (j >= 1 && j <= RSTRIP) {
          TAPS(a10, a11, a12, pla, pa0, pa1, pra, j - 1)
          TAPS(b10, b11, b12, plb, pb0, pb1, prb, j - 1)
        }
        if (j >= 2) {
          TAPS(a20, a21, a22, pla, pa0, pa1, pra, j - 2)
          TAPS(b20, b21, b22, plb, pb0, pb1, prb, j - 2)
        }
#undef TAPS
      }
    }
  }

  // reduce the two i-halves through LDS (lane-major: conflict-free)
  __shared__ float red[4][RSTRIP * 2][64];   // 16 KB
  if (ihalf == 1) {
#pragma unroll
    for (int r = 0; r < RSTRIP; ++r) {
      red[w4][r * 2 + 0][lane] = acc[r][0];
      red[w4][r * 2 + 1][lane] = acc[r][1];
    }
  }
  __syncthreads();
  if (ihalf == 0) {
    float* yb = y + (((size_t)b * 32 + o) * 128 + r0) * 128 + c0;
#pragma unroll
    for (int r = 0; r < RSTRIP; ++r) {
      const float v0 = acc[r][0] + red[w4][r * 2 + 0][lane];
      const float v1 = acc[r][1] + red[w4][r * 2 + 1][lane];
      *(float2*)(yb + (size_t)r * 128) = make_float2(v0, v1);
    }
  }
}

__global__ __launch_bounds__(256) void mix1x1(
    const float* __restrict__ y,    // (B, O, H*W)
    const float* __restrict__ fw,   // (O_out, O_in)
    float* __restrict__ out)        // (B, O, H*W)
{
  const int px = blockIdx.x * 256 + threadIdx.x;  // 0..16383
  const int b  = blockIdx.y;
  const float* yb = y + (size_t)b * 32 * 16384 + px;
  float v[32];
#pragma unroll
  for (int o = 0; o < 32; ++o) v[o] = yb[(size_t)o * 16384];
  float* ob = out + (size_t)b * 32 * 16384 + px;
#pragma unroll
  for (int p = 0; p < 32; ++p) {
    float a = 0.f;
#pragma unroll
    for (int o = 0; o < 32; ++o) a = fmaf(fw[p * 32 + o], v[o], a);
    ob[(size_t)p * 16384] = a;
  }
}

extern "C" void kernel_launch(void* const* d_in, const int* in_sizes, int n_in,
                              void* d_out, int out_size, void* d_ws, size_t ws_size,
                              hipStream_t stream) {
  const float* x     = (const float*)d_in[0];
  const float* scale = (const float*)d_in[1];
  const float* trans = (const float*)d_in[2];
  const float* wconv = (const float*)d_in[3];
  const float* fw    = (const float*)d_in[4];
  float* out = (float*)d_out;
  float* y   = (float*)d_ws;   // 4*32*128*128 floats = 8.39 MB

  const float mhc = (float)(2.0 / (sqrt(3.0) * pow(M_PI, 0.25)));

  dim3 g1(128 / RSTRIP, 8, 4);   // (strips, o-groups of 4, b) = 512 blocks x 512 thr
  wavelet_grouped_conv<<<g1, 512, 0, stream>>>(x, scale, trans, wconv, y, mhc);

  dim3 g2(16384 / 256, 4);       // (pixel tiles, b)
  mix1x1<<<g2, 256, 0, stream>>>(y, fw, out);
}